// Round 11
// baseline (90.710 us; speedup 1.0000x reference)
//
#include <hip/hip_runtime.h>

// Pipeline: k0 W->fragment-packed Wf(16x16 shape) -> k1 barrier-free streaming
// QKV (direct global A-frags, 1:1 W-load:MFMA, zero LDS) -> k2 attention.
// fp16 MFMA 16x16x32: A row=lane&15,k=8*(lane>>4)+i; B col=lane&15,k=8*(lane>>4)+i;
//                     C/D col=lane&15, row=4*(lane>>4)+reg.

#define B_ 256
#define T_ 256
#define C_ 384
#define H_ 64

typedef __attribute__((ext_vector_type(4)))  float     f32x4;
typedef __attribute__((ext_vector_type(8)))  _Float16  f16x8;

#define MFMA16(a, b, c) __builtin_amdgcn_mfma_f32_16x16x32_f16((a), (b), (c), 0, 0, 0)

// ---------------- workspace layout (bytes) ----------------
constexpr size_t WF_OFF = 0;                       // 192*384*2 = 147456 B (frag-packed)
constexpr size_t QH_OFF = 147456;                  // [65536][64] f16, pre-scaled
constexpr size_t KH_OFF = QH_OFF + 8388608;        // [65536][64] f16
constexpr size_t VT_OFF = KH_OFF + 8388608;        // [256][64][256] f16 (V^T per batch)

// ================= k0: W -> Wf (cast + 16x16 fragment layout) =================
// Wf[e]: e = ((nt*12+kk)*64 + lane)*8 + i. Lane (l15,hi) holds B-frag elem
// col=nt*16+l15, k=kk*32+hi*8+i. One (nt,kk) chunk = contiguous 1KB wave-load.
__global__ void w_fragpack(const float* __restrict__ Wq,
                           const float* __restrict__ Wk,
                           const float* __restrict__ Wv,
                           _Float16* __restrict__ Wf) {
    int e = blockIdx.x * 256 + threadIdx.x;      // 0..73727
    int i    = e & 7;
    int lane = (e >> 3) & 63;
    int l15  = lane & 15, hi = lane >> 4;
    int cid  = e >> 9;                            // nt*12 + kk, 0..143
    int kk   = cid % 12;
    int nt   = cid / 12;
    int col  = nt * 16 + l15;                     // 0..191 in [Q|K|V]
    int p    = col >> 6;
    int h    = col & 63;
    int k    = kk * 32 + hi * 8 + i;
    const float* W = (p == 0) ? Wq : (p == 1) ? Wk : Wv;
    Wf[e] = (_Float16)W[k * 64 + h];
}

// ================= k1: QKV = x @ [Wq|Wk|Wv], barrier-free streaming ==========
// 512 blocks x 256 threads (4 fully-independent waves). Wave: 32 rows (2 slabs
// of 16), all 192 cols. No LDS, no barriers. Per kk: 4 x-prefetch loads,
// 12 W-frag loads (1KB each, L1/L2-hot), 24 MFMA.
__global__ __launch_bounds__(256, 3) void qkv_gemm(
    const float* __restrict__ x, const _Float16* __restrict__ Wf,
    _Float16* __restrict__ Qh, _Float16* __restrict__ Kh,
    _Float16* __restrict__ Vt)
{
    const int tid = threadIdx.x, lane = tid & 63, w = tid >> 6;
    const int l15 = lane & 15, hi = lane >> 4;
    const int gid = blockIdx.x * 4 + w;           // 0..2047
    const int row0 = gid * 32;
    const float* xp0 = x + (size_t)(row0 + l15) * C_ + 8 * hi;
    const float* xp1 = xp0 + (size_t)16 * C_;

    f32x4 acc[12][2] = {};                        // [ntile][slab], 96 VGPR

    f32x4 a0 = *(const f32x4*)xp0, a1 = *(const f32x4*)(xp0 + 4);
    f32x4 b0 = *(const f32x4*)xp1, b1 = *(const f32x4*)(xp1 + 4);
    const _Float16* wb = Wf + (size_t)lane * 8;

    #pragma unroll
    for (int kk = 0; kk < 12; ++kk) {
        f32x4 na0, na1, nb0, nb1;
        if (kk < 11) {                            // prefetch next k-chunk
            na0 = *(const f32x4*)(xp0 + (kk + 1) * 32);
            na1 = *(const f32x4*)(xp0 + (kk + 1) * 32 + 4);
            nb0 = *(const f32x4*)(xp1 + (kk + 1) * 32);
            nb1 = *(const f32x4*)(xp1 + (kk + 1) * 32 + 4);
        }
        f16x8 af = {(_Float16)a0.x, (_Float16)a0.y, (_Float16)a0.z, (_Float16)a0.w,
                    (_Float16)a1.x, (_Float16)a1.y, (_Float16)a1.z, (_Float16)a1.w};
        f16x8 bf = {(_Float16)b0.x, (_Float16)b0.y, (_Float16)b0.z, (_Float16)b0.w,
                    (_Float16)b1.x, (_Float16)b1.y, (_Float16)b1.z, (_Float16)b1.w};
        #pragma unroll
        for (int nt = 0; nt < 12; ++nt) {
            f16x8 wfr = *(const f16x8*)(wb + (size_t)(nt * 12 + kk) * 512);
            if (nt < 8) {                          // Q,K: D[t][n]
                acc[nt][0] = MFMA16(af, wfr, acc[nt][0]);
                acc[nt][1] = MFMA16(bf, wfr, acc[nt][1]);
            } else {                               // V: D[h][t] (operand swap)
                acc[nt][0] = MFMA16(wfr, af, acc[nt][0]);
                acc[nt][1] = MFMA16(wfr, bf, acc[nt][1]);
            }
        }
        a0 = na0; a1 = na1; b0 = nb0; b1 = nb1;
    }

    // ---- stores: 16-lane x 2B = 32B sectors, fully utilized ----
    const int b = row0 >> 8;
    const int tbase = row0 & 255;
    #pragma unroll
    for (int s = 0; s < 2; ++s) {
        #pragma unroll
        for (int nt = 0; nt < 4; ++nt)
            #pragma unroll
            for (int reg = 0; reg < 4; ++reg) {
                int t = row0 + s * 16 + 4 * hi + reg;
                Qh[(size_t)t * 64 + nt * 16 + l15] = (_Float16)(0.125f * acc[nt][s][reg]);
                Kh[(size_t)t * 64 + nt * 16 + l15] = (_Float16)acc[nt + 4][s][reg];
            }
        #pragma unroll
        for (int nt = 8; nt < 12; ++nt)
            #pragma unroll
            for (int reg = 0; reg < 4; ++reg) {
                int h  = (nt - 8) * 16 + 4 * hi + reg;
                int tl = tbase + s * 16 + l15;
                Vt[(size_t)b * 16384 + (size_t)h * 256 + tl] = (_Float16)acc[nt][s][reg];
            }
    }
}

// ================= k2: attention per batch =================
// 256 blocks x 512 threads (8 indep waves, 32 q-rows each). LDS only for P-bounce.
constexpr int SP = 72;

__global__ __launch_bounds__(512, 2) void attn(
    const _Float16* __restrict__ Qh, const _Float16* __restrict__ Kh,
    const _Float16* __restrict__ Vt, float* __restrict__ out)
{
    __shared__ _Float16 Ps[8 * 32 * SP];
    const int tid = threadIdx.x, lane = tid & 63, wid = tid >> 6;
    const int lo = lane & 15, hi = lane >> 4;
    const int b = blockIdx.x;
    const int ctmax = 2 * wid + 1;               // last S column-tile with valid entries

    f16x8 aq[2][2];
    #pragma unroll
    for (int rt = 0; rt < 2; ++rt)
        #pragma unroll
        for (int ks = 0; ks < 2; ++ks)
            aq[rt][ks] = *(const f16x8*)(Qh + (size_t)(b * 256 + 32 * wid + 16 * rt + lo) * 64
                                         + 32 * ks + 8 * hi);

    f32x4 sacc[2][16] = {};
    #pragma unroll
    for (int ct = 0; ct < 16; ++ct) {
        if (ct <= ctmax) {
            #pragma unroll
            for (int ks = 0; ks < 2; ++ks) {
                f16x8 bk = *(const f16x8*)(Kh + (size_t)(b * 256 + 16 * ct + lo) * 64
                                           + 32 * ks + 8 * hi);
                sacc[0][ct] = MFMA16(aq[0][ks], bk, sacc[0][ct]);
                sacc[1][ct] = MFMA16(aq[1][ks], bk, sacc[1][ct]);
            }
        }
    }

    #pragma unroll
    for (int rt = 0; rt < 2; ++rt) {
        #pragma unroll
        for (int reg = 0; reg < 4; ++reg) {
            const int rowg = 32 * wid + 16 * rt + 4 * hi + reg;
            float m = -1e30f;
            #pragma unroll
            for (int ct = 0; ct < 16; ++ct) if (ct <= ctmax) {
                float v = sacc[rt][ct][reg];
                v = (16 * ct + lo <= rowg) ? v : -1e30f;
                sacc[rt][ct][reg] = v;
                m = fmaxf(m, v);
            }
            #pragma unroll
            for (int s = 1; s < 16; s <<= 1) m = fmaxf(m, __shfl_xor(m, s, 16));
            float l = 0.f;
            #pragma unroll
            for (int ct = 0; ct < 16; ++ct) if (ct <= ctmax) {
                float v = sacc[rt][ct][reg];
                float p = (v > -1e29f) ? __expf(v - m) : 0.f;
                sacc[rt][ct][reg] = p;
                l += p;
            }
            #pragma unroll
            for (int s = 1; s < 16; s <<= 1) l += __shfl_xor(l, s, 16);
            float rinv = 1.f / l;
            #pragma unroll
            for (int ct = 0; ct < 16; ++ct) if (ct <= ctmax) sacc[rt][ct][reg] *= rinv;
        }
    }

    f32x4 oacc[2][4] = {};
    _Float16* Pw = Ps + wid * 32 * SP;
    const int kcmax = ctmax >> 2;
    #pragma unroll
    for (int kc = 0; kc < 4; ++kc) {
        if (kc <= kcmax) {
            #pragma unroll
            for (int rt = 0; rt < 2; ++rt)
                #pragma unroll
                for (int c = 0; c < 4; ++c) {
                    const int ct = 4 * kc + c;
                    #pragma unroll
                    for (int reg = 0; reg < 4; ++reg) {
                        float v = (ct <= ctmax) ? sacc[rt][ct][reg] : 0.f;
                        Pw[(16 * rt + 4 * hi + reg) * SP + c * 16 + lo] = (_Float16)v;
                    }
                }
            asm volatile("s_waitcnt lgkmcnt(0)" ::: "memory");
            #pragma unroll
            for (int ks = 0; ks < 2; ++ks) {
                f16x8 a0 = *(const f16x8*)(Pw + lo * SP + 32 * ks + 8 * hi);
                f16x8 a1 = *(const f16x8*)(Pw + (16 + lo) * SP + 32 * ks + 8 * hi);
                #pragma unroll
                for (int ht = 0; ht < 4; ++ht) {
                    f16x8 bv = *(const f16x8*)(Vt + (size_t)b * 16384 + (size_t)(16 * ht + lo) * 256
                                               + 64 * kc + 32 * ks + 8 * hi);
                    oacc[0][ht] = MFMA16(a0, bv, oacc[0][ht]);
                    oacc[1][ht] = MFMA16(a1, bv, oacc[1][ht]);
                }
            }
            asm volatile("s_waitcnt lgkmcnt(0)" ::: "memory");
        }
    }

    float* ob = out + (size_t)b * (T_ * H_);
    #pragma unroll
    for (int rt = 0; rt < 2; ++rt)
        #pragma unroll
        for (int ht = 0; ht < 4; ++ht)
            #pragma unroll
            for (int reg = 0; reg < 4; ++reg) {
                const int t = 32 * wid + 16 * rt + 4 * hi + reg;
                ob[t * H_ + 16 * ht + lo] = oacc[rt][ht][reg];
            }
}

extern "C" void kernel_launch(void* const* d_in, const int* in_sizes, int n_in,
                              void* d_out, int out_size, void* d_ws, size_t ws_size,
                              hipStream_t stream) {
    const float* x  = (const float*)d_in[0];
    const float* Wq = (const float*)d_in[1];
    const float* Wk = (const float*)d_in[2];
    const float* Wv = (const float*)d_in[3];
    float* out = (float*)d_out;
    (void)in_sizes; (void)n_in; (void)out_size; (void)ws_size;

    char* ws = (char*)d_ws;
    _Float16* Wf = (_Float16*)(ws + WF_OFF);
    _Float16* Qh = (_Float16*)(ws + QH_OFF);
    _Float16* Kh = (_Float16*)(ws + KH_OFF);
    _Float16* Vt = (_Float16*)(ws + VT_OFF);

    w_fragpack<<<dim3(288), dim3(256), 0, stream>>>(Wq, Wk, Wv, Wf);
    qkv_gemm<<<dim3(512), dim3(256), 0, stream>>>(x, Wf, Qh, Kh, Vt);
    attn<<<dim3(B_), dim3(512), 0, stream>>>(Qh, Kh, Vt, out);
}

// Round 13
// 62.905 us; speedup vs baseline: 1.4420x; 1.4420x over previous
//
#include <hip/hip_runtime.h>

// Pipeline: k0 W->fragment-packed Wf(16x16 shape) -> k1 thin-block high-TLP QKV
// (4 waves/block, acc[3], 24 waves/CU target) -> k2 attention.
// fp16 MFMA 16x16x32: A row=lane&15,k=8*(lane>>4)+i; B col=lane&15,k=8*(lane>>4)+i;
//                     C/D col=lane&15, row=4*(lane>>4)+reg.
// A-frag and B-frag share the lane mapping -> one x fragment serves Q/K (D[t][n])
// and V with Wv as A-operand (D[h][t]).

#define B_ 256
#define T_ 256
#define C_ 384
#define H_ 64

typedef __attribute__((ext_vector_type(4)))  float     f32x4;
typedef __attribute__((ext_vector_type(8)))  _Float16  f16x8;

#define MFMA16(a, b, c) __builtin_amdgcn_mfma_f32_16x16x32_f16((a), (b), (c), 0, 0, 0)

// ---------------- workspace layout (bytes) ----------------
constexpr size_t WF_OFF = 0;                       // 192*384*2 = 147456 B (frag-packed)
constexpr size_t QH_OFF = 147456;                  // [65536][64] f16, pre-scaled
constexpr size_t KH_OFF = QH_OFF + 8388608;        // [65536][64] f16
constexpr size_t VT_OFF = KH_OFF + 8388608;        // [256][64][256] f16 (V^T per batch)

// ================= k0: W -> Wf (cast + 16x16 fragment layout) =================
// Wf[e]: e = ((nt*12+kk)*64 + lane)*8 + i. Lane (l15,hi) holds frag elem
// col=nt*16+l15, k=kk*32+hi*8+i. One (nt,kk) chunk = contiguous 1KB wave-load.
__global__ void w_fragpack(const float* __restrict__ Wq,
                           const float* __restrict__ Wk,
                           const float* __restrict__ Wv,
                           _Float16* __restrict__ Wf) {
    int e = blockIdx.x * 256 + threadIdx.x;      // 0..73727
    int i    = e & 7;
    int lane = (e >> 3) & 63;
    int l15  = lane & 15, hi = lane >> 4;
    int cid  = e >> 9;                            // nt*12 + kk, 0..143
    int kk   = cid % 12;
    int nt   = cid / 12;
    int col  = nt * 16 + l15;                     // 0..191 in [Q|K|V]
    int p    = col >> 6;
    int h    = col & 63;
    int k    = kk * 32 + hi * 8 + i;
    const float* W = (p == 0) ? Wq : (p == 1) ? Wk : Wv;
    Wf[e] = (_Float16)W[k * 64 + h];
}

// ================= k1: QKV = x @ [Wq|Wk|Wv], thin blocks / high TLP ==========
// 4096 blocks x 256 threads (4 waves). Panel = 16 rows. Wave w owns column
// tiles {w (Q), 4+w (K), 8+w (V)}: acc[3] = 12 VGPR. LDS = 12KB x-tile
// (swizzled, reused for repack). Target 6 blocks/CU = 24 waves/CU.
__global__ __launch_bounds__(256, 6) void qkv_gemm(
    const float* __restrict__ x, const _Float16* __restrict__ Wf,
    _Float16* __restrict__ Qh, _Float16* __restrict__ Kh,
    _Float16* __restrict__ Vt)
{
    __shared__ _Float16 xs[16 * 384];             // 12 KB; 16B-group g = c8 ^ (row&15)

    const int tid = threadIdx.x, lane = tid & 63, w = tid >> 6;
    const int l15 = lane & 15, hi = lane >> 4;
    const int pg  = blockIdx.x;                   // panel: rows pg*16..+15
    const float* xp = x + (size_t)pg * 16 * C_;

    // ---- stage x[16][384] fp32 -> fp16 LDS, linear/coalesced ----
    #pragma unroll
    for (int i = 0; i < 3; ++i) {
        int chunk = tid + i * 256;                // 0..767 : 8-float chunks
        int row = chunk / 48, c8 = chunk - row * 48;
        const float* gp = xp + row * C_ + c8 * 8;
        float4 u = *(const float4*)gp;
        float4 v = *(const float4*)(gp + 4);
        f16x8 hv = {(_Float16)u.x, (_Float16)u.y, (_Float16)u.z, (_Float16)u.w,
                    (_Float16)v.x, (_Float16)v.y, (_Float16)v.z, (_Float16)v.w};
        int g = c8 ^ (row & 15);
        *(f16x8*)(xs + row * 384 + g * 8) = hv;
    }
    __syncthreads();

    // ---- compute: 12 kk x {1 ds_read + 3 W-loads (1KB contig, L1-hot) + 3 MFMA} ----
    // K-chunk of 32 halfs = 4 groups of 8; this lane needs group kk*4 + hi.
    f32x4 acc0 = {}, acc1 = {}, acc2 = {};
    const _Float16* wb = Wf + (size_t)lane * 8;
    const int nt0 = w, nt1 = 4 + w, nt2 = 8 + w;
    #pragma unroll
    for (int kk = 0; kk < 12; ++kk) {
        f16x8 xf = *(const f16x8*)(xs + l15 * 384 + (((kk * 4 + hi) ^ l15) * 8));
        f16x8 w0 = *(const f16x8*)(wb + (size_t)(nt0 * 12 + kk) * 512);
        f16x8 w1 = *(const f16x8*)(wb + (size_t)(nt1 * 12 + kk) * 512);
        f16x8 w2 = *(const f16x8*)(wb + (size_t)(nt2 * 12 + kk) * 512);
        acc0 = MFMA16(xf, w0, acc0);              // Q: D[t][n]
        acc1 = MFMA16(xf, w1, acc1);              // K: D[t][n]
        acc2 = MFMA16(w2, xf, acc2);              // V: D[h][t] (operand swap)
    }
    __syncthreads();                              // all waves done reading xs

    // ---- repack into xs (reused): Q[16][64]@0, K@1024, V[64][16]@2048 ----
    #pragma unroll
    for (int reg = 0; reg < 4; ++reg) {
        int t = 4 * hi + reg;                     // local row (Q/K) / local t (V col)
        xs[t * 64 + w * 16 + l15]        = (_Float16)(0.125f * acc0[reg]);   // Q
        xs[1024 + t * 64 + w * 16 + l15] = (_Float16)acc1[reg];              // K
        int hV = w * 16 + 4 * hi + reg;           // V: row=h, col=l15 (t)
        xs[2048 + hV * 16 + l15]         = (_Float16)acc2[reg];
    }
    __syncthreads();

    // ---- coalesced stores (full 128B lines for Q/K; 32B t-chunks for V) ----
    const int b = pg >> 4, tbase = (pg & 15) * 16;
    #pragma unroll
    for (int i = 0; i < 2; ++i) {
        int c = tid + i * 256;                    // 0..511, valid < 384
        if (c < 384) {
            f16x8 vv = *(const f16x8*)(xs + c * 8);
            if (c < 128) {
                int row = c >> 3, n8 = c & 7;
                *(f16x8*)(Qh + (size_t)(pg * 16 + row) * 64 + n8 * 8) = vv;
            } else if (c < 256) {
                int c2 = c - 128, row = c2 >> 3, n8 = c2 & 7;
                *(f16x8*)(Kh + (size_t)(pg * 16 + row) * 64 + n8 * 8) = vv;
            } else {
                int c3 = c - 256, h = c3 >> 1, t8 = c3 & 1;
                *(f16x8*)(Vt + (size_t)b * 16384 + (size_t)h * 256 + tbase + t8 * 8) = vv;
            }
        }
    }
}

// ================= k2: attention per batch =================
// 256 blocks x 512 threads (8 indep waves, 32 q-rows each). LDS only for P-bounce.
constexpr int SP = 72;

__global__ __launch_bounds__(512, 2) void attn(
    const _Float16* __restrict__ Qh, const _Float16* __restrict__ Kh,
    const _Float16* __restrict__ Vt, float* __restrict__ out)
{
    __shared__ _Float16 Ps[8 * 32 * SP];
    const int tid = threadIdx.x, lane = tid & 63, wid = tid >> 6;
    const int lo = lane & 15, hi = lane >> 4;
    const int b = blockIdx.x;
    const int ctmax = 2 * wid + 1;               // last S column-tile with valid entries

    f16x8 aq[2][2];
    #pragma unroll
    for (int rt = 0; rt < 2; ++rt)
        #pragma unroll
        for (int ks = 0; ks < 2; ++ks)
            aq[rt][ks] = *(const f16x8*)(Qh + (size_t)(b * 256 + 32 * wid + 16 * rt + lo) * 64
                                         + 32 * ks + 8 * hi);

    f32x4 sacc[2][16] = {};
    #pragma unroll
    for (int ct = 0; ct < 16; ++ct) {
        if (ct <= ctmax) {
            #pragma unroll
            for (int ks = 0; ks < 2; ++ks) {
                f16x8 bk = *(const f16x8*)(Kh + (size_t)(b * 256 + 16 * ct + lo) * 64
                                           + 32 * ks + 8 * hi);
                sacc[0][ct] = MFMA16(aq[0][ks], bk, sacc[0][ct]);
                sacc[1][ct] = MFMA16(aq[1][ks], bk, sacc[1][ct]);
            }
        }
    }

    #pragma unroll
    for (int rt = 0; rt < 2; ++rt) {
        #pragma unroll
        for (int reg = 0; reg < 4; ++reg) {
            const int rowg = 32 * wid + 16 * rt + 4 * hi + reg;
            float m = -1e30f;
            #pragma unroll
            for (int ct = 0; ct < 16; ++ct) if (ct <= ctmax) {
                float v = sacc[rt][ct][reg];
                v = (16 * ct + lo <= rowg) ? v : -1e30f;
                sacc[rt][ct][reg] = v;
                m = fmaxf(m, v);
            }
            #pragma unroll
            for (int s = 1; s < 16; s <<= 1) m = fmaxf(m, __shfl_xor(m, s, 16));
            float l = 0.f;
            #pragma unroll
            for (int ct = 0; ct < 16; ++ct) if (ct <= ctmax) {
                float v = sacc[rt][ct][reg];
                float p = (v > -1e29f) ? __expf(v - m) : 0.f;
                sacc[rt][ct][reg] = p;
                l += p;
            }
            #pragma unroll
            for (int s = 1; s < 16; s <<= 1) l += __shfl_xor(l, s, 16);
            float rinv = 1.f / l;
            #pragma unroll
            for (int ct = 0; ct < 16; ++ct) if (ct <= ctmax) sacc[rt][ct][reg] *= rinv;
        }
    }

    f32x4 oacc[2][4] = {};
    _Float16* Pw = Ps + wid * 32 * SP;
    const int kcmax = ctmax >> 2;
    #pragma unroll
    for (int kc = 0; kc < 4; ++kc) {
        if (kc <= kcmax) {
            #pragma unroll
            for (int rt = 0; rt < 2; ++rt)
                #pragma unroll
                for (int c = 0; c < 4; ++c) {
                    const int ct = 4 * kc + c;
                    #pragma unroll
                    for (int reg = 0; reg < 4; ++reg) {
                        float v = (ct <= ctmax) ? sacc[rt][ct][reg] : 0.f;
                        Pw[(16 * rt + 4 * hi + reg) * SP + c * 16 + lo] = (_Float16)v;
                    }
                }
            asm volatile("s_waitcnt lgkmcnt(0)" ::: "memory");
            #pragma unroll
            for (int ks = 0; ks < 2; ++ks) {
                f16x8 a0 = *(const f16x8*)(Pw + lo * SP + 32 * ks + 8 * hi);
                f16x8 a1 = *(const f16x8*)(Pw + (16 + lo) * SP + 32 * ks + 8 * hi);
                #pragma unroll
                for (int ht = 0; ht < 4; ++ht) {
                    f16x8 bv = *(const f16x8*)(Vt + (size_t)b * 16384 + (size_t)(16 * ht + lo) * 256
                                               + 64 * kc + 32 * ks + 8 * hi);
                    oacc[0][ht] = MFMA16(a0, bv, oacc[0][ht]);
                    oacc[1][ht] = MFMA16(a1, bv, oacc[1][ht]);
                }
            }
            asm volatile("s_waitcnt lgkmcnt(0)" ::: "memory");
        }
    }

    float* ob = out + (size_t)b * (T_ * H_);
    #pragma unroll
    for (int rt = 0; rt < 2; ++rt)
        #pragma unroll
        for (int ht = 0; ht < 4; ++ht)
            #pragma unroll
            for (int reg = 0; reg < 4; ++reg) {
                const int t = 32 * wid + 16 * rt + 4 * hi + reg;
                ob[t * H_ + 16 * ht + lo] = oacc[rt][ht][reg];
            }
}

extern "C" void kernel_launch(void* const* d_in, const int* in_sizes, int n_in,
                              void* d_out, int out_size, void* d_ws, size_t ws_size,
                              hipStream_t stream) {
    const float* x  = (const float*)d_in[0];
    const float* Wq = (const float*)d_in[1];
    const float* Wk = (const float*)d_in[2];
    const float* Wv = (const float*)d_in[3];
    float* out = (float*)d_out;
    (void)in_sizes; (void)n_in; (void)out_size; (void)ws_size;

    char* ws = (char*)d_ws;
    _Float16* Wf = (_Float16*)(ws + WF_OFF);
    _Float16* Qh = (_Float16*)(ws + QH_OFF);
    _Float16* Kh = (_Float16*)(ws + KH_OFF);
    _Float16* Vt = (_Float16*)(ws + VT_OFF);

    w_fragpack<<<dim3(288), dim3(256), 0, stream>>>(Wq, Wk, Wv, Wf);
    qkv_gemm<<<dim3(4096), dim3(256), 0, stream>>>(x, Wf, Qh, Kh, Vt);
    attn<<<dim3(B_), dim3(512), 0, stream>>>(Qh, Kh, Vt, out);
}

// Round 15
// 43.645 us; speedup vs baseline: 2.0783x; 1.4413x over previous
//
#include <hip/hip_runtime.h>

// Fully fused per-batch kernel: QKV projection (streamed K-chunks, reg-prefetch
// staging) + causal attention, all intermediates in LDS.
// k0 packs W into 16x16 MFMA fragment order (verified R13).
// fp16 MFMA 16x16x32: A row=lane&15,k=8*(lane>>4)+i; B col=lane&15,k=8*(lane>>4)+i;
//                     C/D col=lane&15, row=4*(lane>>4)+reg.
// A/B share lane mapping -> one x fragment serves Q/K (D[t][n]) and V with Wv
// as A-operand (D[h][t]).

#define B_ 256
#define T_ 256
#define C_ 384
#define H_ 64

typedef __attribute__((ext_vector_type(4))) float     f32x4;
typedef __attribute__((ext_vector_type(8))) _Float16  f16x8;

#define MFMA16(a, b, c) __builtin_amdgcn_mfma_f32_16x16x32_f16((a), (b), (c), 0, 0, 0)

// ---------------- LDS layout (halfs) ----------------
constexpr int SQ = 72;                      // Qs/Ks stride
constexpr int SV = 264;                     // Vt stride
constexpr int SP = 72;                      // Ps stride
constexpr int OFF_K = 256 * SQ;             // 18432
constexpr int OFF_V = 2 * 256 * SQ;         // 36864
constexpr int OFF_X = OFF_V + 64 * SV;      // 53760 (x chunk [256][40]; Ps reuses)
constexpr int OFF_W = OFF_X + 256 * 40;     // 64000 (W chunk, 12 nt x 64 lanes x 8)
// Ps (phase B) spans OFF_X .. OFF_X + 8*32*SP = 72192 (overlaps XB+WS, both dead
// in phase B). Allocation must cover it:
constexpr int SMEM_HALFS = OFF_X + 8 * 32 * SP;   // 72192  (OFF_W+6144=70144 < this)
constexpr int SMEM_BYTES = SMEM_HALFS * 2;        // 144384 B (< 160 KiB)

// ================= k0: W -> Wf (cast + 16x16 fragment layout; verified R13) ==
// Wf[e]: e = ((nt*12+kk)*64 + lane)*8 + i ; lane (l15,hi) holds elem
// col=nt*16+l15, k=kk*32+hi*8+i. One (nt,kk) chunk = contiguous 1KB.
__global__ void w_fragpack(const float* __restrict__ Wq,
                           const float* __restrict__ Wk,
                           const float* __restrict__ Wv,
                           _Float16* __restrict__ Wf) {
    int e = blockIdx.x * 256 + threadIdx.x;      // 0..73727
    int i    = e & 7;
    int lane = (e >> 3) & 63;
    int l15  = lane & 15, hi = lane >> 4;
    int cid  = e >> 9;                            // nt*12 + kk
    int kk   = cid % 12;
    int nt   = cid / 12;
    int col  = nt * 16 + l15;
    int p    = col >> 6;
    int h    = col & 63;
    int k    = kk * 32 + hi * 8 + i;
    const float* W = (p == 0) ? Wq : (p == 1) ? Wk : Wv;
    Wf[e] = (_Float16)W[k * 64 + h];
}

// ================= fused kernel: one block per batch =================
__global__ __launch_bounds__(512, 1) void head_fused(
    const float* __restrict__ x, const _Float16* __restrict__ Wf,
    float* __restrict__ out)
{
    extern __shared__ _Float16 sm[];
    _Float16* Qs = sm;                 // [256][SQ], pre-scaled
    _Float16* Ks = sm + OFF_K;         // [256][SQ]
    _Float16* Vt = sm + OFF_V;         // [64][SV]
    _Float16* XB = sm + OFF_X;         // [256][40] per-chunk x tile
    _Float16* WS = sm + OFF_W;         // [12][64][8] per-chunk W frags
    _Float16* Ps = sm + OFF_X;         // phase-B P bounce (reuses XB/WS span)

    const int tid = threadIdx.x, lane = tid & 63, wid = tid >> 6;
    const int lo = lane & 15, hi = lane >> 4;
    const int b = blockIdx.x;
    const float* xb = x + (size_t)b * T_ * C_;

    // staging geometry:
    // x chunk c: 1024 f16x8-slots: id = tid + i*512 (i=0,1); row=id>>2, g=id&3
    //   global: xb + row*C_ + c*32 + g*8 (8 floats)   LDS: XB[row*40 + g*8]
    // W chunk c: 768 slots: id0 = tid; id1 = 512+tid (tid<256); nt=id>>6, l=id&63
    //   global: Wf + ((nt*12+c)*64 + l)*8             LDS: WS[id*8]

    // ---- prologue: stage chunk 0 ----
    float4 xu0[2], xu1[2];
    f16x8  wv0, wv1;
    {
        #pragma unroll
        for (int i = 0; i < 2; ++i) {
            int id = tid + i * 512, row = id >> 2, g = id & 3;
            const float* gp = xb + row * C_ + 0 * 32 + g * 8;
            float4 a = *(const float4*)gp, c4 = *(const float4*)(gp + 4);
            if (i == 0) { xu0[0] = a; xu0[1] = c4; } else { xu1[0] = a; xu1[1] = c4; }
        }
        { int id = tid, nt = id >> 6, l = id & 63;
          wv0 = *(const f16x8*)(Wf + ((size_t)(nt * 12 + 0) * 64 + l) * 8); }
        if (tid < 256) { int id = 512 + tid, nt = id >> 6, l = id & 63;
          wv1 = *(const f16x8*)(Wf + ((size_t)(nt * 12 + 0) * 64 + l) * 8); }
        #pragma unroll
        for (int i = 0; i < 2; ++i) {
            int id = tid + i * 512, row = id >> 2, g = id & 3;
            float4 a = (i == 0) ? xu0[0] : xu1[0];
            float4 c4 = (i == 0) ? xu0[1] : xu1[1];
            f16x8 hv = {(_Float16)a.x, (_Float16)a.y, (_Float16)a.z, (_Float16)a.w,
                        (_Float16)c4.x, (_Float16)c4.y, (_Float16)c4.z, (_Float16)c4.w};
            *(f16x8*)(XB + row * 40 + g * 8) = hv;
        }
        *(f16x8*)(WS + tid * 8) = wv0;
        if (tid < 256) *(f16x8*)(WS + (512 + tid) * 8) = wv1;
    }
    __syncthreads();

    // ---- K-chunk loop: compute chunk c, prefetch c+1 in regs ----
    f32x4 acc[12][2] = {};                 // [col-tile][row-slab], 96 VGPR
    #pragma unroll
    for (int c = 0; c < 12; ++c) {
        // issue next-chunk global loads (latency hides under compute)
        if (c < 11) {
            #pragma unroll
            for (int i = 0; i < 2; ++i) {
                int id = tid + i * 512, row = id >> 2, g = id & 3;
                const float* gp = xb + row * C_ + (c + 1) * 32 + g * 8;
                float4 a = *(const float4*)gp, c4 = *(const float4*)(gp + 4);
                if (i == 0) { xu0[0] = a; xu0[1] = c4; } else { xu1[0] = a; xu1[1] = c4; }
            }
            { int id = tid, nt = id >> 6, l = id & 63;
              wv0 = *(const f16x8*)(Wf + ((size_t)(nt * 12 + c + 1) * 64 + l) * 8); }
            if (tid < 256) { int id = 512 + tid, nt = id >> 6, l = id & 63;
              wv1 = *(const f16x8*)(Wf + ((size_t)(nt * 12 + c + 1) * 64 + l) * 8); }
        }

        // compute chunk c
        f16x8 a0 = *(const f16x8*)(XB + (32 * wid + lo) * 40 + hi * 8);
        f16x8 a1 = *(const f16x8*)(XB + (32 * wid + 16 + lo) * 40 + hi * 8);
        #pragma unroll
        for (int nt = 0; nt < 8; ++nt) {           // Q (0-3), K (4-7): D[t][n]
            f16x8 wf = *(const f16x8*)(WS + (nt * 64 + lane) * 8);
            acc[nt][0] = MFMA16(a0, wf, acc[nt][0]);
            acc[nt][1] = MFMA16(a1, wf, acc[nt][1]);
        }
        #pragma unroll
        for (int nt = 8; nt < 12; ++nt) {          // V: D[h][t] (operand swap)
            f16x8 wf = *(const f16x8*)(WS + (nt * 64 + lane) * 8);
            acc[nt][0] = MFMA16(wf, a0, acc[nt][0]);
            acc[nt][1] = MFMA16(wf, a1, acc[nt][1]);
        }
        __syncthreads();                           // done reading XB/WS

        // write prefetched chunk
        if (c < 11) {
            #pragma unroll
            for (int i = 0; i < 2; ++i) {
                int id = tid + i * 512, row = id >> 2, g = id & 3;
                float4 a = (i == 0) ? xu0[0] : xu1[0];
                float4 c4 = (i == 0) ? xu0[1] : xu1[1];
                f16x8 hv = {(_Float16)a.x, (_Float16)a.y, (_Float16)a.z, (_Float16)a.w,
                            (_Float16)c4.x, (_Float16)c4.y, (_Float16)c4.z, (_Float16)c4.w};
                *(f16x8*)(XB + row * 40 + g * 8) = hv;
            }
            *(f16x8*)(WS + tid * 8) = wv0;
            if (tid < 256) *(f16x8*)(WS + (512 + tid) * 8) = wv1;
            __syncthreads();
        }
    }

    // ---- epilogue: acc -> Qs (pre-scaled) / Ks / Vt ----
    #pragma unroll
    for (int nt = 0; nt < 4; ++nt)
        #pragma unroll
        for (int s = 0; s < 2; ++s)
            #pragma unroll
            for (int reg = 0; reg < 4; ++reg) {
                int t = 32 * wid + s * 16 + 4 * hi + reg;
                Qs[t * SQ + nt * 16 + lo] = (_Float16)(0.125f * acc[nt][s][reg]);
            }
    #pragma unroll
    for (int nt = 4; nt < 8; ++nt)
        #pragma unroll
        for (int s = 0; s < 2; ++s)
            #pragma unroll
            for (int reg = 0; reg < 4; ++reg) {
                int t = 32 * wid + s * 16 + 4 * hi + reg;
                Ks[t * SQ + (nt - 4) * 16 + lo] = (_Float16)acc[nt][s][reg];
            }
    #pragma unroll
    for (int nt = 8; nt < 12; ++nt)
        #pragma unroll
        for (int s = 0; s < 2; ++s)
            #pragma unroll
            for (int reg = 0; reg < 4; ++reg) {
                int h = (nt - 8) * 16 + 4 * hi + reg;
                int t = 32 * wid + s * 16 + lo;
                Vt[h * SV + t] = (_Float16)acc[nt][s][reg];
            }
    __syncthreads();

    // ---- phase B: causal attention (verified R1 structure, LDS operands) ----
    const int ctmax = 2 * wid + 1;

    f16x8 aq[2][2];
    #pragma unroll
    for (int rt = 0; rt < 2; ++rt)
        #pragma unroll
        for (int ks = 0; ks < 2; ++ks)
            aq[rt][ks] = *(const f16x8*)(Qs + (32 * wid + 16 * rt + lo) * SQ + 32 * ks + 8 * hi);

    f32x4 sacc[2][16] = {};
    #pragma unroll
    for (int ct = 0; ct < 16; ++ct) {
        if (ct <= ctmax) {
            #pragma unroll
            for (int ks = 0; ks < 2; ++ks) {
                f16x8 bk = *(const f16x8*)(Ks + (16 * ct + lo) * SQ + 32 * ks + 8 * hi);
                sacc[0][ct] = MFMA16(aq[0][ks], bk, sacc[0][ct]);
                sacc[1][ct] = MFMA16(aq[1][ks], bk, sacc[1][ct]);
            }
        }
    }

    #pragma unroll
    for (int rt = 0; rt < 2; ++rt) {
        #pragma unroll
        for (int reg = 0; reg < 4; ++reg) {
            const int rowg = 32 * wid + 16 * rt + 4 * hi + reg;
            float m = -1e30f;
            #pragma unroll
            for (int ct = 0; ct < 16; ++ct) if (ct <= ctmax) {
                float v = sacc[rt][ct][reg];
                v = (16 * ct + lo <= rowg) ? v : -1e30f;
                sacc[rt][ct][reg] = v;
                m = fmaxf(m, v);
            }
            #pragma unroll
            for (int s = 1; s < 16; s <<= 1) m = fmaxf(m, __shfl_xor(m, s, 16));
            float l = 0.f;
            #pragma unroll
            for (int ct = 0; ct < 16; ++ct) if (ct <= ctmax) {
                float v = sacc[rt][ct][reg];
                float p = (v > -1e29f) ? __expf(v - m) : 0.f;
                sacc[rt][ct][reg] = p;
                l += p;
            }
            #pragma unroll
            for (int s = 1; s < 16; s <<= 1) l += __shfl_xor(l, s, 16);
            float rinv = 1.f / l;
            #pragma unroll
            for (int ct = 0; ct < 16; ++ct) if (ct <= ctmax) sacc[rt][ct][reg] *= rinv;
        }
    }

    f32x4 oacc[2][4] = {};
    _Float16* Pw = Ps + wid * 32 * SP;
    const int kcmax = ctmax >> 2;
    #pragma unroll
    for (int kc = 0; kc < 4; ++kc) {
        if (kc <= kcmax) {
            #pragma unroll
            for (int rt = 0; rt < 2; ++rt)
                #pragma unroll
                for (int cc = 0; cc < 4; ++cc) {
                    const int ct = 4 * kc + cc;
                    #pragma unroll
                    for (int reg = 0; reg < 4; ++reg) {
                        float v = (ct <= ctmax) ? sacc[rt][ct][reg] : 0.f;
                        Pw[(16 * rt + 4 * hi + reg) * SP + cc * 16 + lo] = (_Float16)v;
                    }
                }
            asm volatile("s_waitcnt lgkmcnt(0)" ::: "memory");
            #pragma unroll
            for (int ks = 0; ks < 2; ++ks) {
                f16x8 p0 = *(const f16x8*)(Pw + lo * SP + 32 * ks + 8 * hi);
                f16x8 p1 = *(const f16x8*)(Pw + (16 + lo) * SP + 32 * ks + 8 * hi);
                #pragma unroll
                for (int ht = 0; ht < 4; ++ht) {
                    f16x8 bv = *(const f16x8*)(Vt + (16 * ht + lo) * SV + 64 * kc + 32 * ks + 8 * hi);
                    oacc[0][ht] = MFMA16(p0, bv, oacc[0][ht]);
                    oacc[1][ht] = MFMA16(p1, bv, oacc[1][ht]);
                }
            }
            asm volatile("s_waitcnt lgkmcnt(0)" ::: "memory");
        }
    }

    float* ob = out + (size_t)b * (T_ * H_);
    #pragma unroll
    for (int rt = 0; rt < 2; ++rt)
        #pragma unroll
        for (int ht = 0; ht < 4; ++ht)
            #pragma unroll
            for (int reg = 0; reg < 4; ++reg) {
                const int t = 32 * wid + 16 * rt + 4 * hi + reg;
                ob[t * H_ + 16 * ht + lo] = oacc[rt][ht][reg];
            }
}

extern "C" void kernel_launch(void* const* d_in, const int* in_sizes, int n_in,
                              void* d_out, int out_size, void* d_ws, size_t ws_size,
                              hipStream_t stream) {
    const float* x  = (const float*)d_in[0];
    const float* Wq = (const float*)d_in[1];
    const float* Wk = (const float*)d_in[2];
    const float* Wv = (const float*)d_in[3];
    float* out = (float*)d_out;
    (void)in_sizes; (void)n_in; (void)out_size; (void)ws_size;

    _Float16* Wf = (_Float16*)d_ws;                 // 147456 B

    w_fragpack<<<dim3(288), dim3(256), 0, stream>>>(Wq, Wk, Wv, Wf);
    hipFuncSetAttribute(reinterpret_cast<const void*>(head_fused),
                        hipFuncAttributeMaxDynamicSharedMemorySize, SMEM_BYTES);
    head_fused<<<dim3(B_), dim3(512), SMEM_BYTES, stream>>>(x, Wf, out);
}

// Round 16
// 41.112 us; speedup vs baseline: 2.2064x; 1.0616x over previous
//
#include <hip/hip_runtime.h>

// Fully fused per-batch kernel: QKV projection + causal attention, intermediates
// in LDS. R15 + (a) raw s_barrier with lgkmcnt-only drain (keeps prefetch loads
// in flight across barriers), (b) 2-deep register prefetch (sets A/B by parity).
// fp16 MFMA 16x16x32: A row=lane&15,k=8*(lane>>4)+i; B col=lane&15,k=8*(lane>>4)+i;
//                     C/D col=lane&15, row=4*(lane>>4)+reg.

#define B_ 256
#define T_ 256
#define C_ 384
#define H_ 64

typedef __attribute__((ext_vector_type(4))) float     f32x4;
typedef __attribute__((ext_vector_type(8))) _Float16  f16x8;

#define MFMA16(a, b, c) __builtin_amdgcn_mfma_f32_16x16x32_f16((a), (b), (c), 0, 0, 0)
#define LGKM_BARRIER() do { asm volatile("s_waitcnt lgkmcnt(0)" ::: "memory"); \
                            __builtin_amdgcn_s_barrier(); } while (0)

// ---------------- LDS layout (halfs) ----------------
constexpr int SQ = 72;                      // Qs/Ks stride
constexpr int SV = 264;                     // Vt stride
constexpr int SP = 72;                      // Ps stride
constexpr int OFF_K = 256 * SQ;             // 18432
constexpr int OFF_V = 2 * 256 * SQ;         // 36864
constexpr int OFF_X = OFF_V + 64 * SV;      // 53760 (x chunk [256][40]; Ps reuses)
constexpr int OFF_W = OFF_X + 256 * 40;     // 64000 (W chunk, 12 nt x 64 lanes x 8)
constexpr int SMEM_HALFS = OFF_X + 8 * 32 * SP;   // 72192 (covers Ps span)
constexpr int SMEM_BYTES = SMEM_HALFS * 2;        // 144384 B

// ================= k0: W -> Wf (16x16 fragment layout; verified) =============
__global__ void w_fragpack(const float* __restrict__ Wq,
                           const float* __restrict__ Wk,
                           const float* __restrict__ Wv,
                           _Float16* __restrict__ Wf) {
    int e = blockIdx.x * 256 + threadIdx.x;      // 0..73727
    int i    = e & 7;
    int lane = (e >> 3) & 63;
    int l15  = lane & 15, hi = lane >> 4;
    int cid  = e >> 9;                            // nt*12 + kk
    int kk   = cid % 12;
    int nt   = cid / 12;
    int col  = nt * 16 + l15;
    int p    = col >> 6;
    int h    = col & 63;
    int k    = kk * 32 + hi * 8 + i;
    const float* W = (p == 0) ? Wq : (p == 1) ? Wk : Wv;
    Wf[e] = (_Float16)W[k * 64 + h];
}

// ---- staging helpers (constant-indexed arrays -> registers) ----
__device__ __forceinline__ void issue_chunk(const float* xb, const _Float16* Wf,
    int tid, int c, float4 (&xu)[4], f16x8& w0, f16x8& w1)
{
    #pragma unroll
    for (int i = 0; i < 2; ++i) {
        int id = tid + i * 512, row = id >> 2, g = id & 3;
        const float* gp = xb + row * C_ + c * 32 + g * 8;
        xu[2 * i]     = *(const float4*)gp;
        xu[2 * i + 1] = *(const float4*)(gp + 4);
    }
    { int nt = tid >> 6, l = tid & 63;
      w0 = *(const f16x8*)(Wf + ((size_t)(nt * 12 + c) * 64 + l) * 8); }
    if (tid < 256) { int id = 512 + tid, nt = id >> 6, l = id & 63;
      w1 = *(const f16x8*)(Wf + ((size_t)(nt * 12 + c) * 64 + l) * 8); }
}

__device__ __forceinline__ void write_chunk(_Float16* XB, _Float16* WS,
    int tid, const float4 (&xu)[4], const f16x8& w0, const f16x8& w1)
{
    #pragma unroll
    for (int i = 0; i < 2; ++i) {
        int id = tid + i * 512, row = id >> 2, g = id & 3;
        const float4& a = xu[2 * i];
        const float4& b = xu[2 * i + 1];
        f16x8 hv = {(_Float16)a.x, (_Float16)a.y, (_Float16)a.z, (_Float16)a.w,
                    (_Float16)b.x, (_Float16)b.y, (_Float16)b.z, (_Float16)b.w};
        *(f16x8*)(XB + row * 40 + g * 8) = hv;
    }
    *(f16x8*)(WS + tid * 8) = w0;
    if (tid < 256) *(f16x8*)(WS + (512 + tid) * 8) = w1;
}

// ================= fused kernel: one block per batch =================
__global__ __launch_bounds__(512, 1) void head_fused(
    const float* __restrict__ x, const _Float16* __restrict__ Wf,
    float* __restrict__ out)
{
    extern __shared__ _Float16 sm[];
    _Float16* Qs = sm;                 // [256][SQ], pre-scaled
    _Float16* Ks = sm + OFF_K;         // [256][SQ]
    _Float16* Vt = sm + OFF_V;         // [64][SV]
    _Float16* XB = sm + OFF_X;         // [256][40] per-chunk x tile
    _Float16* WS = sm + OFF_W;         // [12][64][8] per-chunk W frags
    _Float16* Ps = sm + OFF_X;         // phase-B P bounce (reuses XB/WS span)

    const int tid = threadIdx.x, lane = tid & 63, wid = tid >> 6;
    const int lo = lane & 15, hi = lane >> 4;
    const int b = blockIdx.x;
    const float* xb = x + (size_t)b * T_ * C_;

    // ---- prologue: issue chunks 0,1 (2-deep), write chunk 0 ----
    float4 xA[4], xB2[4];
    f16x8  wA0, wA1, wB0, wB1;
    issue_chunk(xb, Wf, tid, 0, xA, wA0, wA1);
    issue_chunk(xb, Wf, tid, 1, xB2, wB0, wB1);
    write_chunk(XB, WS, tid, xA, wA0, wA1);       // auto counted-vmcnt wait (set A)
    LGKM_BARRIER();

    // ---- K-chunk loop: 2 raw barriers/chunk, loads stay in flight ----
    f32x4 acc[12][2] = {};                 // [col-tile][row-slab]
    #pragma unroll
    for (int c = 0; c < 12; ++c) {
        // issue chunk c+2 into the parity set freed by chunk c's write
        if (c + 2 < 12) {
            if ((c & 1) == 0) issue_chunk(xb, Wf, tid, c + 2, xA, wA0, wA1);
            else              issue_chunk(xb, Wf, tid, c + 2, xB2, wB0, wB1);
        }

        // compute chunk c
        f16x8 a0 = *(const f16x8*)(XB + (32 * wid + lo) * 40 + hi * 8);
        f16x8 a1 = *(const f16x8*)(XB + (32 * wid + 16 + lo) * 40 + hi * 8);
        #pragma unroll
        for (int nt = 0; nt < 8; ++nt) {           // Q (0-3), K (4-7): D[t][n]
            f16x8 wf = *(const f16x8*)(WS + (nt * 64 + lane) * 8);
            acc[nt][0] = MFMA16(a0, wf, acc[nt][0]);
            acc[nt][1] = MFMA16(a1, wf, acc[nt][1]);
        }
        #pragma unroll
        for (int nt = 8; nt < 12; ++nt) {          // V: D[h][t] (operand swap)
            f16x8 wf = *(const f16x8*)(WS + (nt * 64 + lane) * 8);
            acc[nt][0] = MFMA16(wf, a0, acc[nt][0]);
            acc[nt][1] = MFMA16(wf, a1, acc[nt][1]);
        }

        if (c < 11) {
            LGKM_BARRIER();                        // all waves done reading XB/WS
            // write chunk c+1 from set ((c+1)&1); data issued ~2 chunks ago
            if ((c & 1) == 0) write_chunk(XB, WS, tid, xB2, wB0, wB1);
            else              write_chunk(XB, WS, tid, xA, wA0, wA1);
            LGKM_BARRIER();                        // writes visible to all waves
        }
    }

    // ---- epilogue: acc -> Qs (pre-scaled) / Ks / Vt (disjoint from XB/WS) ----
    #pragma unroll
    for (int nt = 0; nt < 4; ++nt)
        #pragma unroll
        for (int s = 0; s < 2; ++s)
            #pragma unroll
            for (int reg = 0; reg < 4; ++reg) {
                int t = 32 * wid + s * 16 + 4 * hi + reg;
                Qs[t * SQ + nt * 16 + lo] = (_Float16)(0.125f * acc[nt][s][reg]);
            }
    #pragma unroll
    for (int nt = 4; nt < 8; ++nt)
        #pragma unroll
        for (int s = 0; s < 2; ++s)
            #pragma unroll
            for (int reg = 0; reg < 4; ++reg) {
                int t = 32 * wid + s * 16 + 4 * hi + reg;
                Ks[t * SQ + (nt - 4) * 16 + lo] = (_Float16)acc[nt][s][reg];
            }
    #pragma unroll
    for (int nt = 8; nt < 12; ++nt)
        #pragma unroll
        for (int s = 0; s < 2; ++s)
            #pragma unroll
            for (int reg = 0; reg < 4; ++reg) {
                int h = (nt - 8) * 16 + 4 * hi + reg;
                int t = 32 * wid + s * 16 + lo;
                Vt[h * SV + t] = (_Float16)acc[nt][s][reg];
            }
    __syncthreads();

    // ---- phase B: causal attention (verified structure, LDS operands) ----
    const int ctmax = 2 * wid + 1;

    f16x8 aq[2][2];
    #pragma unroll
    for (int rt = 0; rt < 2; ++rt)
        #pragma unroll
        for (int ks = 0; ks < 2; ++ks)
            aq[rt][ks] = *(const f16x8*)(Qs + (32 * wid + 16 * rt + lo) * SQ + 32 * ks + 8 * hi);

    f32x4 sacc[2][16] = {};
    #pragma unroll
    for (int ct = 0; ct < 16; ++ct) {
        if (ct <= ctmax) {
            #pragma unroll
            for (int ks = 0; ks < 2; ++ks) {
                f16x8 bk = *(const f16x8*)(Ks + (16 * ct + lo) * SQ + 32 * ks + 8 * hi);
                sacc[0][ct] = MFMA16(aq[0][ks], bk, sacc[0][ct]);
                sacc[1][ct] = MFMA16(aq[1][ks], bk, sacc[1][ct]);
            }
        }
    }

    #pragma unroll
    for (int rt = 0; rt < 2; ++rt) {
        #pragma unroll
        for (int reg = 0; reg < 4; ++reg) {
            const int rowg = 32 * wid + 16 * rt + 4 * hi + reg;
            float m = -1e30f;
            #pragma unroll
            for (int ct = 0; ct < 16; ++ct) if (ct <= ctmax) {
                float v = sacc[rt][ct][reg];
                v = (16 * ct + lo <= rowg) ? v : -1e30f;
                sacc[rt][ct][reg] = v;
                m = fmaxf(m, v);
            }
            #pragma unroll
            for (int s = 1; s < 16; s <<= 1) m = fmaxf(m, __shfl_xor(m, s, 16));
            float l = 0.f;
            #pragma unroll
            for (int ct = 0; ct < 16; ++ct) if (ct <= ctmax) {
                float v = sacc[rt][ct][reg];
                float p = (v > -1e29f) ? __expf(v - m) : 0.f;
                sacc[rt][ct][reg] = p;
                l += p;
            }
            #pragma unroll
            for (int s = 1; s < 16; s <<= 1) l += __shfl_xor(l, s, 16);
            float rinv = 1.f / l;
            #pragma unroll
            for (int ct = 0; ct < 16; ++ct) if (ct <= ctmax) sacc[rt][ct][reg] *= rinv;
        }
    }

    f32x4 oacc[2][4] = {};
    _Float16* Pw = Ps + wid * 32 * SP;
    const int kcmax = ctmax >> 2;
    #pragma unroll
    for (int kc = 0; kc < 4; ++kc) {
        if (kc <= kcmax) {
            #pragma unroll
            for (int rt = 0; rt < 2; ++rt)
                #pragma unroll
                for (int cc = 0; cc < 4; ++cc) {
                    const int ct = 4 * kc + cc;
                    #pragma unroll
                    for (int reg = 0; reg < 4; ++reg) {
                        float v = (ct <= ctmax) ? sacc[rt][ct][reg] : 0.f;
                        Pw[(16 * rt + 4 * hi + reg) * SP + cc * 16 + lo] = (_Float16)v;
                    }
                }
            asm volatile("s_waitcnt lgkmcnt(0)" ::: "memory");
            #pragma unroll
            for (int ks = 0; ks < 2; ++ks) {
                f16x8 p0 = *(const f16x8*)(Pw + lo * SP + 32 * ks + 8 * hi);
                f16x8 p1 = *(const f16x8*)(Pw + (16 + lo) * SP + 32 * ks + 8 * hi);
                #pragma unroll
                for (int ht = 0; ht < 4; ++ht) {
                    f16x8 bv = *(const f16x8*)(Vt + (16 * ht + lo) * SV + 64 * kc + 32 * ks + 8 * hi);
                    oacc[0][ht] = MFMA16(p0, bv, oacc[0][ht]);
                    oacc[1][ht] = MFMA16(p1, bv, oacc[1][ht]);
                }
            }
            asm volatile("s_waitcnt lgkmcnt(0)" ::: "memory");
        }
    }

    float* ob = out + (size_t)b * (T_ * H_);
    #pragma unroll
    for (int rt = 0; rt < 2; ++rt)
        #pragma unroll
        for (int ht = 0; ht < 4; ++ht)
            #pragma unroll
            for (int reg = 0; reg < 4; ++reg) {
                const int t = 32 * wid + 16 * rt + 4 * hi + reg;
                ob[t * H_ + 16 * ht + lo] = oacc[rt][ht][reg];
            }
}

extern "C" void kernel_launch(void* const* d_in, const int* in_sizes, int n_in,
                              void* d_out, int out_size, void* d_ws, size_t ws_size,
                              hipStream_t stream) {
    const float* x  = (const float*)d_in[0];
    const float* Wq = (const float*)d_in[1];
    const float* Wk = (const float*)d_in[2];
    const float* Wv = (const float*)d_in[3];
    float* out = (float*)d_out;
    (void)in_sizes; (void)n_in; (void)out_size; (void)ws_size;

    _Float16* Wf = (_Float16*)d_ws;                 // 147456 B

    w_fragpack<<<dim3(288), dim3(256), 0, stream>>>(Wq, Wk, Wv, Wf);
    hipFuncSetAttribute(reinterpret_cast<const void*>(head_fused),
                        hipFuncAttributeMaxDynamicSharedMemorySize, SMEM_BYTES);
    head_fused<<<dim3(B_), dim3(512), SMEM_BYTES, stream>>>(x, Wf, out);
}